// Round 1
// baseline (603.634 us; speedup 1.0000x reference)
//
#include <hip/hip_runtime.h>
#include <hip/hip_bf16.h>

// sLSTM block, MI355X. One fused bf16 MFMA GEMM
//   P[g] = [x|h] (4096x4096) @ [Wg|Rg]^T (2048x4096), g in {z,i,f,o}
// with gating epilogue fused (LDS exchange of the 4 gate tiles).
// R4: T3+T4+T5 pipeline on the GEMM K-loop.
//   - triple-buffered LDS staging (3 x 48KB = 144KB, 1 block/CU by design)
//   - prefetch depth 2, counted s_waitcnt vmcnt(6) (never 0 in main loop)
//   - raw s_barrier (no implicit vmcnt drain), 2 MFMA phases per K-step
//   - s_setprio(1) around each 16-MFMA cluster
// ws: A_bf16 [4096][4096] @0 (32MB) | Wb_bf16 [4][2048][4096] @32MB (64MB)
//     | Bb fp32 [4][2048] @96MB.

#define BATCH 4096
#define NHID  2048
#define KDIM  4096
#define NTOT  8388608L   // BATCH*NHID
#define AW_OFS 16777216  // elements from A base to W base in ws
#define BUFSZ 49152      // one stage buffer: A 16KB + B 32KB

typedef float  f32x4   __attribute__((ext_vector_type(4)));
typedef short  short8  __attribute__((ext_vector_type(8)));
typedef unsigned short ushort8 __attribute__((ext_vector_type(8)));

#define GL_LDS16(gp, lp)                                                      \
    __builtin_amdgcn_global_load_lds(                                         \
        (const __attribute__((address_space(1))) void*)(gp),                  \
        (__attribute__((address_space(3))) void*)(lp), 16, 0, 0)

__device__ __forceinline__ unsigned short f2bf(float f) {
    unsigned u = __float_as_uint(f);
    unsigned r = (u + 0x7fffu + ((u >> 16) & 1u)) >> 16;   // RNE
    return (unsigned short)r;
}

// ---- fp32 -> bf16 pack of A = [x | h_prev], 4096 x 4096 -------------------
__global__ void convA_kernel(const float* __restrict__ x,
                             const float* __restrict__ h,
                             unsigned short* __restrict__ A) {
    int gid = blockIdx.x * 256 + threadIdx.x;       // 4096*512 groups of 8
    int row = gid >> 9;
    int col = (gid & 511) << 3;
    const float* src = (col < 2048) ? (x + (long)row * 2048 + col)
                                    : (h + (long)row * 2048 + (col - 2048));
    f32x4 v0 = __builtin_nontemporal_load((const f32x4*)src);
    f32x4 v1 = __builtin_nontemporal_load((const f32x4*)src + 1);
    ushort8 o;
    o[0] = f2bf(v0[0]); o[1] = f2bf(v0[1]); o[2] = f2bf(v0[2]); o[3] = f2bf(v0[3]);
    o[4] = f2bf(v1[0]); o[5] = f2bf(v1[1]); o[6] = f2bf(v1[2]); o[7] = f2bf(v1[3]);
    *(ushort8*)(A + ((long)row << 12) + col) = o;
}

// ---- fp32 -> bf16 pack of Wb[g][j][k] (k<2048: Wg, k>=2048: Rg) -----------
__global__ void convW_kernel(const float* __restrict__ w0, const float* __restrict__ w1,
                             const float* __restrict__ w2, const float* __restrict__ w3,
                             const float* __restrict__ w4, const float* __restrict__ w5,
                             const float* __restrict__ w6, const float* __restrict__ w7,
                             unsigned short* __restrict__ Wb) {
    int z = blockIdx.y;                              // 0..3 = Wzx..Wox, 4..7 = Rzh..Roh
    const float* src;
    switch (z) {
        case 0: src = w0; break; case 1: src = w1; break;
        case 2: src = w2; break; case 3: src = w3; break;
        case 4: src = w4; break; case 5: src = w5; break;
        case 6: src = w6; break; default: src = w7; break;
    }
    int gid = blockIdx.x * 256 + threadIdx.x;        // 2048*256 groups of 8
    int row = gid >> 8;
    int col = (gid & 255) << 3;
    const float* p = src + (long)row * 2048 + col;
    f32x4 v0 = __builtin_nontemporal_load((const f32x4*)p);
    f32x4 v1 = __builtin_nontemporal_load((const f32x4*)p + 1);
    ushort8 o;
    o[0] = f2bf(v0[0]); o[1] = f2bf(v0[1]); o[2] = f2bf(v0[2]); o[3] = f2bf(v0[3]);
    o[4] = f2bf(v1[0]); o[5] = f2bf(v1[1]); o[6] = f2bf(v1[2]); o[7] = f2bf(v1[3]);
    int g = z & 3, hf = z >> 2;
    *(ushort8*)(Wb + (long)g * NHID * KDIM + (long)row * KDIM + hf * 2048 + col) = o;
}

// ---- combined bias Bb[g][j] = Wg_b[j] + Rg_b[j] ---------------------------
__global__ void bias_kernel(const float* __restrict__ b0, const float* __restrict__ b1,
                            const float* __restrict__ b2, const float* __restrict__ b3,
                            const float* __restrict__ r0, const float* __restrict__ r1,
                            const float* __restrict__ r2, const float* __restrict__ r3,
                            float* __restrict__ Bb) {
    int gid = blockIdx.x * 256 + threadIdx.x;        // 0..8191
    int g = gid >> 11, j = gid & 2047;
    const float *wb, *rb;
    switch (g) {
        case 0: wb = b0; rb = r0; break; case 1: wb = b1; rb = r1; break;
        case 2: wb = b2; rb = r2; break; default: wb = b3; rb = r3; break;
    }
    Bb[gid] = wb[j] + rb[j];
}

// ---- fused GEMM (4 gates) + sLSTM epilogue --------------------------------
// block: 512 threads = 8 waves; wave w: gate = w&3, rowhalf = w>>2.
// Each wave computes a 64x64 tile of its gate (4x4 of 16x16x32 MFMA).
// grid: (32 row-tiles of 128, 32 col-tiles of 64); x fastest (W-slice L2 share).
// LDS: 3 stage buffers of 48KB: A [128 rows][8 x 16B] @0, B [4][64][8 x 16B] @16KB.
// XOR swizzle: chunk (r, jj) holds k-chunk jj^(r&7)  (conflict-free ds_read_b128).
// Pipeline: iter kt reads buf[kt%3], stages tile kt+2 into buf[(kt+2)%3]
// (3 loads per phase); vmcnt(6) at iter top retires tile kt's 6 loads only.
__global__ __launch_bounds__(512, 2) void slstm_kernel(
    const __hip_bfloat16* __restrict__ A,    // [4096][4096], W follows at +AW_OFS
    const float* __restrict__ Bb,            // [4][2048]
    const float* __restrict__ c_prev,
    const float* __restrict__ n_prev,
    const float* __restrict__ m_prev,
    float* __restrict__ out)                 // h | c | n | m
{
    __shared__ uint4 smem4[3 * BUFSZ / 16];  // 144 KB
    char* smem = (char*)smem4;

    const int tid  = threadIdx.x;
    const int lane = tid & 63;
    const int wv   = tid >> 6;     // wave id 0..7
    const int gate = wv & 3;
    const int rh   = wv >> 2;      // row half 0/1
    const int lm   = lane & 15;
    const int quad = lane >> 4;
    const int l7   = lm & 7;

    const int row0 = blockIdx.x * 128;  // batch rows
    const int col0 = blockIdx.y * 64;   // hidden cols

    // staging: 48 loads of 1KB (64 lanes x 16B); wave w issues ids w*6..w*6+5.
    // ids 0..15 -> A tile (128 x 64), ids 16..47 -> B tiles (4 x 64 x 64).
    int gofs[6]; int lofs[6];
#pragma unroll
    for (int t = 0; t < 6; ++t) {
        int id = wv * 6 + t;
        if (id < 16) {
            int idx = id * 64 + lane;                // 0..1023
            int r = idx >> 3, jj = idx & 7;
            int j = jj ^ (r & 7);
            gofs[t] = (row0 + r) * KDIM + j * 8;
            lofs[t] = id * 1024;
        } else {
            int idx = (id - 16) * 64 + lane;         // 0..2047
            int g = idx >> 9, rr = (idx >> 3) & 63, jj = idx & 7;
            int j = jj ^ (rr & 7);
            gofs[t] = AW_OFS + (g * NHID + col0 + rr) * KDIM + j * 8;
            lofs[t] = 16384 + (id - 16) * 1024;
        }
    }

    f32x4 acc[4][4];
#pragma unroll
    for (int mt = 0; mt < 4; ++mt)
#pragma unroll
        for (int nt = 0; nt < 4; ++nt)
#pragma unroll
            for (int r = 0; r < 4; ++r) acc[mt][nt][r] = 0.0f;

    const int aofs = rh * 8192;                 // rowhalf A base (within buffer)
    const int bofs = 16384 + gate * 8192;       // gate B base (within buffer)

    // prologue: stage tile 0 -> buf0, tile 1 -> buf1 (12 loads in flight)
#pragma unroll
    for (int t = 0; t < 6; ++t) GL_LDS16(A + gofs[t], smem + lofs[t]);
#pragma unroll
    for (int t = 0; t < 6; ++t) GL_LDS16(A + gofs[t] + 64, smem + BUFSZ + lofs[t]);

    int cur = 0;
    for (int kt = 0; kt < 64; ++kt) {
        // retire tile kt's 6 loads (oldest); keep later tiles' loads in flight.
        if (kt == 63) { asm volatile("s_waitcnt vmcnt(0)" ::: "memory"); }
        else         { asm volatile("s_waitcnt vmcnt(6)" ::: "memory"); }
        __builtin_amdgcn_s_barrier();            // buf[cur] fully staged for all waves

        const char* base = smem + cur * BUFSZ;
        int nxt = cur - 1; if (nxt < 0) nxt = 2; // (cur+2)%3
        char* nb = smem + nxt * BUFSZ;
        const bool doStage = (kt < 62);
        const int  ko = (kt + 2) * 64;

#pragma unroll
        for (int p = 0; p < 2; ++p) {
            const int cof = ((p * 4 + quad) ^ l7) * 16;
            short8 af[4], bf[4];
#pragma unroll
            for (int mt = 0; mt < 4; ++mt)
                af[mt] = *(const short8*)(base + aofs + (mt * 16 + lm) * 128 + cof);
#pragma unroll
            for (int nt = 0; nt < 4; ++nt)
                bf[nt] = *(const short8*)(base + bofs + (nt * 16 + lm) * 128 + cof);
            if (doStage) {
#pragma unroll
                for (int t = p * 3; t < p * 3 + 3; ++t)
                    GL_LDS16(A + gofs[t] + ko, nb + lofs[t]);
            }
            __builtin_amdgcn_s_barrier();        // phase alignment before MFMA
            __builtin_amdgcn_s_setprio(1);
#pragma unroll
            for (int mt = 0; mt < 4; ++mt)
#pragma unroll
                for (int nt = 0; nt < 4; ++nt)
                    acc[mt][nt] = __builtin_amdgcn_mfma_f32_16x16x32_bf16(
                        af[mt], bf[nt], acc[mt][nt], 0, 0, 0);
            __builtin_amdgcn_s_setprio(0);
        }
        cur = cur + 1; if (cur == 3) cur = 0;
    }

    // ---- epilogue: exchange gate tiles through LDS, compute h,c,n,m ----
    float* exch = (float*)smem;   // [2 rh][4 gates][16 rows][65] floats (33.3KB)
#pragma unroll
    for (int mt = 0; mt < 4; ++mt) {
        __syncthreads();
#pragma unroll
        for (int nt = 0; nt < 4; ++nt)
#pragma unroll
            for (int r = 0; r < 4; ++r)
                exch[((rh * 4 + gate) * 16 + quad * 4 + r) * 65 + nt * 16 + lm] =
                    acc[mt][nt][r];
        __syncthreads();
#pragma unroll
        for (int q = 0; q < 4; ++q) {
            int e   = q * 512 + tid;          // 0..2047
            int erh = e >> 10, row = (e >> 6) & 15, col = e & 63;
            int R = row0 + erh * 64 + mt * 16 + row;
            int C = col0 + col;
            long idx = (long)R * NHID + C;
            float zp = exch[((erh * 4 + 0) * 16 + row) * 65 + col] + Bb[C];
            float ip = exch[((erh * 4 + 1) * 16 + row) * 65 + col] + Bb[2048 + C];
            float fp = exch[((erh * 4 + 2) * 16 + row) * 65 + col] + Bb[4096 + C];
            float op = exch[((erh * 4 + 3) * 16 + row) * 65 + col] + Bb[6144 + C];
            float cp = __builtin_nontemporal_load(c_prev + idx);
            float np = __builtin_nontemporal_load(n_prev + idx);
            float mp = __builtin_nontemporal_load(m_prev + idx);
            float z  = tanhf(zp);
            float o  = 1.0f / (1.0f + __expf(-op));
            float mm = fmaxf(fp + mp, ip);
            float ih = __expf(ip - mm);
            float fh = __expf(fp + mp - mm);
            float cc = fh * cp + ih * z;
            float nn = fh * np + ih;
            float hh = o * cc / nn;
            __builtin_nontemporal_store(hh, out + idx);
            __builtin_nontemporal_store(cc, out + NTOT + idx);
            __builtin_nontemporal_store(nn, out + 2 * NTOT + idx);
            __builtin_nontemporal_store(mm, out + 3 * NTOT + idx);
        }
    }
}

extern "C" void kernel_launch(void* const* d_in, const int* in_sizes, int n_in,
                              void* d_out, int out_size, void* d_ws, size_t ws_size,
                              hipStream_t stream) {
    const float* x      = (const float*)d_in[0];
    const float* h_prev = (const float*)d_in[1];
    const float* c_prev = (const float*)d_in[2];
    const float* n_prev = (const float*)d_in[3];
    const float* m_prev = (const float*)d_in[4];
    unsigned short* A  = (unsigned short*)d_ws;                          // 32 MB
    unsigned short* Wb = (unsigned short*)((char*)d_ws + 33554432);      // 64 MB
    float*          Bb = (float*)((char*)d_ws + 100663296);              // 32 KB

    convA_kernel<<<8192, 256, 0, stream>>>(x, h_prev, A);
    convW_kernel<<<dim3(2048, 8), 256, 0, stream>>>(
        (const float*)d_in[5], (const float*)d_in[7], (const float*)d_in[9],
        (const float*)d_in[11], (const float*)d_in[13], (const float*)d_in[15],
        (const float*)d_in[17], (const float*)d_in[19], Wb);
    bias_kernel<<<32, 256, 0, stream>>>(
        (const float*)d_in[6], (const float*)d_in[8], (const float*)d_in[10],
        (const float*)d_in[12], (const float*)d_in[14], (const float*)d_in[16],
        (const float*)d_in[18], (const float*)d_in[20], Bb);

    slstm_kernel<<<dim3(32, 32), 512, 0, stream>>>(
        (const __hip_bfloat16*)A, Bb, c_prev, n_prev, m_prev, (float*)d_out);
}

// Round 2
// 576.187 us; speedup vs baseline: 1.0476x; 1.0476x over previous
//
#include <hip/hip_runtime.h>
#include <hip/hip_bf16.h>

// sLSTM block, MI355X. One fused bf16 MFMA GEMM
//   P[g] = [x|h] (4096x4096) @ [Wg|Rg]^T (2048x4096), g in {z,i,f,o}
// with gating epilogue fused (LDS exchange of the 4 gate tiles).
// R5: faithful port of the 256^2 8-phase template geometry.
//   - block tile 256 rows x 64 cols x 4 gates (virtual 256x256), BK=64
//   - 8 waves = 2 rowgroups x 4 gates; per-wave output 128x64 (acc[8][4])
//   - 4 phases/K-tile: phase = (kk half, mt half); {reads, stage, barrier,
//     setprio+16 MFMA+setprio, barrier} per phase
//   - LDS 160KB: A double-buffered (2x32KB), B triple-buffered (3x32KB)
//   - one counted s_waitcnt vmcnt(4) per K-tile (phase 3); never 0 mid-loop
// ws: A_bf16 [4096][4096] @0 (32MB) | Wb_bf16 [4][2048][4096] @32MB (64MB)
//     | Bb fp32 [4][2048] @96MB.

#define BATCH 4096
#define NHID  2048
#define KDIM  4096
#define NTOT  8388608L   // BATCH*NHID
#define AW_OFS 16777216  // elements from A base to W base in ws

typedef float  f32x4   __attribute__((ext_vector_type(4)));
typedef short  short8  __attribute__((ext_vector_type(8)));
typedef unsigned short ushort8 __attribute__((ext_vector_type(8)));

#define GL_LDS16(gp, lp)                                                      \
    __builtin_amdgcn_global_load_lds(                                         \
        (const __attribute__((address_space(1))) void*)(gp),                  \
        (__attribute__((address_space(3))) void*)(lp), 16, 0, 0)

__device__ __forceinline__ unsigned short f2bf(float f) {
    unsigned u = __float_as_uint(f);
    unsigned r = (u + 0x7fffu + ((u >> 16) & 1u)) >> 16;   // RNE
    return (unsigned short)r;
}

// ---- fp32 -> bf16 pack of A = [x | h_prev], 4096 x 4096 -------------------
__global__ void convA_kernel(const float* __restrict__ x,
                             const float* __restrict__ h,
                             unsigned short* __restrict__ A) {
    int gid = blockIdx.x * 256 + threadIdx.x;       // 4096*512 groups of 8
    int row = gid >> 9;
    int col = (gid & 511) << 3;
    const float* src = (col < 2048) ? (x + (long)row * 2048 + col)
                                    : (h + (long)row * 2048 + (col - 2048));
    f32x4 v0 = __builtin_nontemporal_load((const f32x4*)src);
    f32x4 v1 = __builtin_nontemporal_load((const f32x4*)src + 1);
    ushort8 o;
    o[0] = f2bf(v0[0]); o[1] = f2bf(v0[1]); o[2] = f2bf(v0[2]); o[3] = f2bf(v0[3]);
    o[4] = f2bf(v1[0]); o[5] = f2bf(v1[1]); o[6] = f2bf(v1[2]); o[7] = f2bf(v1[3]);
    *(ushort8*)(A + ((long)row << 12) + col) = o;
}

// ---- fp32 -> bf16 pack of Wb[g][j][k] (k<2048: Wg, k>=2048: Rg) -----------
__global__ void convW_kernel(const float* __restrict__ w0, const float* __restrict__ w1,
                             const float* __restrict__ w2, const float* __restrict__ w3,
                             const float* __restrict__ w4, const float* __restrict__ w5,
                             const float* __restrict__ w6, const float* __restrict__ w7,
                             unsigned short* __restrict__ Wb) {
    int z = blockIdx.y;                              // 0..3 = Wzx..Wox, 4..7 = Rzh..Roh
    const float* src;
    switch (z) {
        case 0: src = w0; break; case 1: src = w1; break;
        case 2: src = w2; break; case 3: src = w3; break;
        case 4: src = w4; break; case 5: src = w5; break;
        case 6: src = w6; break; default: src = w7; break;
    }
    int gid = blockIdx.x * 256 + threadIdx.x;        // 2048*256 groups of 8
    int row = gid >> 8;
    int col = (gid & 255) << 3;
    const float* p = src + (long)row * 2048 + col;
    f32x4 v0 = __builtin_nontemporal_load((const f32x4*)p);
    f32x4 v1 = __builtin_nontemporal_load((const f32x4*)p + 1);
    ushort8 o;
    o[0] = f2bf(v0[0]); o[1] = f2bf(v0[1]); o[2] = f2bf(v0[2]); o[3] = f2bf(v0[3]);
    o[4] = f2bf(v1[0]); o[5] = f2bf(v1[1]); o[6] = f2bf(v1[2]); o[7] = f2bf(v1[3]);
    int g = z & 3, hf = z >> 2;
    *(ushort8*)(Wb + (long)g * NHID * KDIM + (long)row * KDIM + hf * 2048 + col) = o;
}

// ---- combined bias Bb[g][j] = Wg_b[j] + Rg_b[j] ---------------------------
__global__ void bias_kernel(const float* __restrict__ b0, const float* __restrict__ b1,
                            const float* __restrict__ b2, const float* __restrict__ b3,
                            const float* __restrict__ r0, const float* __restrict__ r1,
                            const float* __restrict__ r2, const float* __restrict__ r3,
                            float* __restrict__ Bb) {
    int gid = blockIdx.x * 256 + threadIdx.x;        // 0..8191
    int g = gid >> 11, j = gid & 2047;
    const float *wb, *rb;
    switch (g) {
        case 0: wb = b0; rb = r0; break; case 1: wb = b1; rb = r1; break;
        case 2: wb = b2; rb = r2; break; default: wb = b3; rb = r3; break;
    }
    Bb[gid] = wb[j] + rb[j];
}

// ---- fused GEMM (4 gates) + sLSTM epilogue --------------------------------
// block: 512 threads = 8 waves; wave w: gate = w&3, rowgroup rg = w>>2.
// Wave computes a 128x64 tile of its gate (8x4 of 16x16x32 MFMA, acc 128 VGPR).
// grid: (16 row-tiles of 256, 32 col-tiles of 64); x fastest (B-panel L2 share).
// LDS 160KB: A buffers [256 rows][8 x 16B] @0,@32K; B buffers [4][64][8x16B]
// @64K,@96K,@128K. XOR swizzle: chunk (r,jj) holds k-chunk jj^(r&7).
// Pipeline: iter kt reads A from ab[kt&1], B from bbuf[kt%3]. Phase 0 issues
// A(kt+1) (4 loads); phases 1-2 issue B(kt+2) (2+2). Phase 3: vmcnt(4)
// retires A(kt+1)+B(kt+1), leaves B(kt+2) in flight.
__global__ __launch_bounds__(512, 2) void slstm_kernel(
    const __hip_bfloat16* __restrict__ A,    // [4096][4096], W follows at +AW_OFS
    const float* __restrict__ Bb,            // [4][2048]
    const float* __restrict__ c_prev,
    const float* __restrict__ n_prev,
    const float* __restrict__ m_prev,
    float* __restrict__ out)                 // h | c | n | m
{
    __shared__ uint4 smem4[163840 / 16];     // 160 KB
    char* smem = (char*)smem4;

    const int tid  = threadIdx.x;
    const int lane = tid & 63;
    const int wv   = tid >> 6;     // wave id 0..7
    const int gate = wv & 3;
    const int rg   = wv >> 2;      // rowgroup 0/1 (128 rows each)
    const int lm   = lane & 15;
    const int quad = lane >> 4;
    const int l7   = lm & 7;

    const int row0 = blockIdx.x * 256;  // batch rows
    const int col0 = blockIdx.y * 64;   // hidden cols

    // fragment ds_read offsets (relative to buffer base); + mt/nt*2048 later
    int aoff[2], boff[2];
#pragma unroll
    for (int kk = 0; kk < 2; ++kk) {
        int cof = ((kk * 4 + quad) ^ l7) * 16;
        aoff[kk] = (rg * 128 + lm) * 128 + cof;
        boff[kk] = (gate * 64 + lm) * 128 + cof;
    }

    // staging: per wave 4 A-loads + 4 B-loads of 1KB (64 lanes x 16B) per tile.
    // A load id a = wv*4+t covers rows 8a..8a+7 (of 256) x full K=64 swizzled.
    // B load id b = wv*4+t covers gate-rows 8b..8b+7 (of 4x64).
    int agofs[4], bgofs[4], lbo[4];
#pragma unroll
    for (int t = 0; t < 4; ++t) {
        int idx = (wv * 4 + t) * 64 + lane;          // 0..2047
        int r = idx >> 3, jj = idx & 7;
        agofs[t] = (row0 + r) * KDIM + (jj ^ (r & 7)) * 8;
        int g = r >> 6, rr = r & 63;
        bgofs[t] = AW_OFS + (g * NHID + col0 + rr) * KDIM + (jj ^ (rr & 7)) * 8;
        lbo[t] = idx * 16;                           // LDS byte off within buffer
    }

    f32x4 acc[8][4];
#pragma unroll
    for (int mt = 0; mt < 8; ++mt)
#pragma unroll
        for (int nt = 0; nt < 4; ++nt)
#pragma unroll
            for (int r = 0; r < 4; ++r) acc[mt][nt][r] = 0.0f;

    int ar = 0,     aw = 32768;                      // A double buffer
    int bc = 65536, bn = 98304, bn2 = 131072;        // B triple buffer

    // prologue: A(0)->ar, B(0)->bc, B(1)->bn  (order matters for vmcnt(4))
#pragma unroll
    for (int t = 0; t < 4; ++t) GL_LDS16(A + agofs[t], smem + ar + lbo[t]);
#pragma unroll
    for (int t = 0; t < 4; ++t) GL_LDS16(A + bgofs[t], smem + bc + lbo[t]);
#pragma unroll
    for (int t = 0; t < 4; ++t) GL_LDS16(A + bgofs[t] + 64, smem + bn + lbo[t]);
    asm volatile("s_waitcnt vmcnt(4)" ::: "memory");  // A(0),B(0) landed; B(1) in flight
    __builtin_amdgcn_s_barrier();

    short8 bf[4];
    for (int kt = 0; kt < 64; ++kt) {
        const char* aB = smem + ar;
        const char* bB = smem + bc;
        char* aW = smem + aw;
        char* bW = smem + bn2;
        const int kA = (kt + 1) * 64;
        const int kB = (kt + 2) * 64;
        const bool stA = kt <= 62, stB = kt <= 61;

#pragma unroll
        for (int p = 0; p < 4; ++p) {
            const int kk = p >> 1;      // phases 0,1: k 0-31; phases 2,3: k 32-63
            const int mh = p & 1;       // mt half 0-3 / 4-7
            if (p == 0 || p == 2) {
#pragma unroll
                for (int nt = 0; nt < 4; ++nt)
                    bf[nt] = *(const short8*)(bB + boff[kk] + nt * 2048);
            }
            short8 af[4];
#pragma unroll
            for (int m2 = 0; m2 < 4; ++m2)
                af[m2] = *(const short8*)(aB + aoff[kk] + (mh * 4 + m2) * 2048);

            if (p == 0 && stA) {
#pragma unroll
                for (int t = 0; t < 4; ++t) GL_LDS16(A + agofs[t] + kA, aW + lbo[t]);
            }
            if (p == 1 && stB) {
                GL_LDS16(A + bgofs[0] + kB, bW + lbo[0]);
                GL_LDS16(A + bgofs[1] + kB, bW + lbo[1]);
            }
            if (p == 2 && stB) {
                GL_LDS16(A + bgofs[2] + kB, bW + lbo[2]);
                GL_LDS16(A + bgofs[3] + kB, bW + lbo[3]);
            }
            if (p == 3 && kt < 63) {
                // retire A(kt+1) and B(kt+1); leave B(kt+2) (4 loads) in flight
                if (kt <= 61) asm volatile("s_waitcnt vmcnt(4)" ::: "memory");
                else          asm volatile("s_waitcnt vmcnt(0)" ::: "memory");
            }
            __builtin_amdgcn_s_barrier();
            __builtin_amdgcn_s_setprio(1);
#pragma unroll
            for (int m2 = 0; m2 < 4; ++m2)
#pragma unroll
                for (int nt = 0; nt < 4; ++nt)
                    acc[mh * 4 + m2][nt] = __builtin_amdgcn_mfma_f32_16x16x32_bf16(
                        af[m2], bf[nt], acc[mh * 4 + m2][nt], 0, 0, 0);
            __builtin_amdgcn_s_setprio(0);
            __builtin_amdgcn_s_barrier();
        }
        // rotate buffers
        int t0 = ar; ar = aw; aw = t0;
        int t1 = bc; bc = bn; bn = bn2; bn2 = t1;
    }

    // ---- epilogue: exchange gate tiles through LDS, compute h,c,n,m ----
    float* exch = (float*)smem;   // [2 rg][4 gates][16 rows][65] floats (33.3KB)
#pragma unroll
    for (int mt = 0; mt < 8; ++mt) {
        __syncthreads();
#pragma unroll
        for (int nt = 0; nt < 4; ++nt)
#pragma unroll
            for (int r = 0; r < 4; ++r)
                exch[((rg * 4 + gate) * 16 + quad * 4 + r) * 65 + nt * 16 + lm] =
                    acc[mt][nt][r];
        __syncthreads();
#pragma unroll
        for (int q = 0; q < 4; ++q) {
            int e   = q * 512 + tid;          // 0..2047
            int erh = e >> 10, row = (e >> 6) & 15, col = e & 63;
            int R = row0 + erh * 128 + mt * 16 + row;
            int C = col0 + col;
            long idx = (long)R * NHID + C;
            float zp = exch[((erh * 4 + 0) * 16 + row) * 65 + col] + Bb[C];
            float ip = exch[((erh * 4 + 1) * 16 + row) * 65 + col] + Bb[2048 + C];
            float fp = exch[((erh * 4 + 2) * 16 + row) * 65 + col] + Bb[4096 + C];
            float op = exch[((erh * 4 + 3) * 16 + row) * 65 + col] + Bb[6144 + C];
            float cp = __builtin_nontemporal_load(c_prev + idx);
            float np = __builtin_nontemporal_load(n_prev + idx);
            float mp = __builtin_nontemporal_load(m_prev + idx);
            float z  = tanhf(zp);
            float o  = 1.0f / (1.0f + __expf(-op));
            float mm = fmaxf(fp + mp, ip);
            float ih = __expf(ip - mm);
            float fh = __expf(fp + mp - mm);
            float cc = fh * cp + ih * z;
            float nn = fh * np + ih;
            float hh = o * cc / nn;
            __builtin_nontemporal_store(hh, out + idx);
            __builtin_nontemporal_store(cc, out + NTOT + idx);
            __builtin_nontemporal_store(nn, out + 2 * NTOT + idx);
            __builtin_nontemporal_store(mm, out + 3 * NTOT + idx);
        }
    }
}

extern "C" void kernel_launch(void* const* d_in, const int* in_sizes, int n_in,
                              void* d_out, int out_size, void* d_ws, size_t ws_size,
                              hipStream_t stream) {
    const float* x      = (const float*)d_in[0];
    const float* h_prev = (const float*)d_in[1];
    const float* c_prev = (const float*)d_in[2];
    const float* n_prev = (const float*)d_in[3];
    const float* m_prev = (const float*)d_in[4];
    unsigned short* A  = (unsigned short*)d_ws;                          // 32 MB
    unsigned short* Wb = (unsigned short*)((char*)d_ws + 33554432);      // 64 MB
    float*          Bb = (float*)((char*)d_ws + 100663296);              // 32 KB

    convA_kernel<<<8192, 256, 0, stream>>>(x, h_prev, A);
    convW_kernel<<<dim3(2048, 8), 256, 0, stream>>>(
        (const float*)d_in[5], (const float*)d_in[7], (const float*)d_in[9],
        (const float*)d_in[11], (const float*)d_in[13], (const float*)d_in[15],
        (const float*)d_in[17], (const float*)d_in[19], Wb);
    bias_kernel<<<32, 256, 0, stream>>>(
        (const float*)d_in[6], (const float*)d_in[8], (const float*)d_in[10],
        (const float*)d_in[12], (const float*)d_in[14], (const float*)d_in[16],
        (const float*)d_in[18], (const float*)d_in[20], Bb);

    slstm_kernel<<<dim3(16, 32), 512, 0, stream>>>(
        (const __hip_bfloat16*)A, Bb, c_prev, n_prev, m_prev, (float*)d_out);
}

// Round 3
// 569.113 us; speedup vs baseline: 1.0607x; 1.0124x over previous
//
#include <hip/hip_runtime.h>
#include <hip/hip_bf16.h>

// sLSTM block, MI355X. One fused bf16 MFMA GEMM
//   P[g] = [x|h] (4096x4096) @ [Wg|Rg]^T (2048x4096), g in {z,i,f,o}
// with gating epilogue fused (LDS exchange of the 4 gate tiles).
// R6: fix pipeline depth asymmetry of the R5 8-phase template port.
//   - block tile 256 rows x 64 cols x 4 gates (virtual 256x256), BK=64
//   - 8 waves = 2 rowgroups x 4 gates; per-wave output 128x64 (acc[8][4])
//   - 4 phases/K-tile: {reads, stage-issue, barrier, setprio+16 MFMA, barrier}
//   - LDS 160KB: A TRIPLE-buffered (3x32KB) <- A is the long-latency operand
//     (same-x blocks share an XCD, A first-touch goes to LLC); B DOUBLE (2x32KB)
//   - issue B(kt+1) at phase 0, A(kt+2) at phases 1-2; vmcnt(4) at phase 3
//     retires {A(kt+1), B(kt+1)}, leaves A(kt+2) in flight (~6 phases slack)
// ws: A_bf16 [4096][4096] @0 (32MB) | Wb_bf16 [4][2048][4096] @32MB (64MB)
//     | Bb fp32 [4][2048] @96MB.

#define BATCH 4096
#define NHID  2048
#define KDIM  4096
#define NTOT  8388608L   // BATCH*NHID
#define AW_OFS 16777216  // elements from A base to W base in ws

typedef float  f32x4   __attribute__((ext_vector_type(4)));
typedef short  short8  __attribute__((ext_vector_type(8)));
typedef unsigned short ushort8 __attribute__((ext_vector_type(8)));

#define GL_LDS16(gp, lp)                                                      \
    __builtin_amdgcn_global_load_lds(                                         \
        (const __attribute__((address_space(1))) void*)(gp),                  \
        (__attribute__((address_space(3))) void*)(lp), 16, 0, 0)

__device__ __forceinline__ unsigned short f2bf(float f) {
    unsigned u = __float_as_uint(f);
    unsigned r = (u + 0x7fffu + ((u >> 16) & 1u)) >> 16;   // RNE
    return (unsigned short)r;
}

// ---- fp32 -> bf16 pack of A = [x | h_prev], 4096 x 4096 -------------------
__global__ void convA_kernel(const float* __restrict__ x,
                             const float* __restrict__ h,
                             unsigned short* __restrict__ A) {
    int gid = blockIdx.x * 256 + threadIdx.x;       // 4096*512 groups of 8
    int row = gid >> 9;
    int col = (gid & 511) << 3;
    const float* src = (col < 2048) ? (x + (long)row * 2048 + col)
                                    : (h + (long)row * 2048 + (col - 2048));
    f32x4 v0 = __builtin_nontemporal_load((const f32x4*)src);
    f32x4 v1 = __builtin_nontemporal_load((const f32x4*)src + 1);
    ushort8 o;
    o[0] = f2bf(v0[0]); o[1] = f2bf(v0[1]); o[2] = f2bf(v0[2]); o[3] = f2bf(v0[3]);
    o[4] = f2bf(v1[0]); o[5] = f2bf(v1[1]); o[6] = f2bf(v1[2]); o[7] = f2bf(v1[3]);
    *(ushort8*)(A + ((long)row << 12) + col) = o;
}

// ---- fp32 -> bf16 pack of Wb[g][j][k] (k<2048: Wg, k>=2048: Rg) -----------
__global__ void convW_kernel(const float* __restrict__ w0, const float* __restrict__ w1,
                             const float* __restrict__ w2, const float* __restrict__ w3,
                             const float* __restrict__ w4, const float* __restrict__ w5,
                             const float* __restrict__ w6, const float* __restrict__ w7,
                             unsigned short* __restrict__ Wb) {
    int z = blockIdx.y;                              // 0..3 = Wzx..Wox, 4..7 = Rzh..Roh
    const float* src;
    switch (z) {
        case 0: src = w0; break; case 1: src = w1; break;
        case 2: src = w2; break; case 3: src = w3; break;
        case 4: src = w4; break; case 5: src = w5; break;
        case 6: src = w6; break; default: src = w7; break;
    }
    int gid = blockIdx.x * 256 + threadIdx.x;        // 2048*256 groups of 8
    int row = gid >> 8;
    int col = (gid & 255) << 3;
    const float* p = src + (long)row * 2048 + col;
    f32x4 v0 = __builtin_nontemporal_load((const f32x4*)p);
    f32x4 v1 = __builtin_nontemporal_load((const f32x4*)p + 1);
    ushort8 o;
    o[0] = f2bf(v0[0]); o[1] = f2bf(v0[1]); o[2] = f2bf(v0[2]); o[3] = f2bf(v0[3]);
    o[4] = f2bf(v1[0]); o[5] = f2bf(v1[1]); o[6] = f2bf(v1[2]); o[7] = f2bf(v1[3]);
    int g = z & 3, hf = z >> 2;
    *(ushort8*)(Wb + (long)g * NHID * KDIM + (long)row * KDIM + hf * 2048 + col) = o;
}

// ---- combined bias Bb[g][j] = Wg_b[j] + Rg_b[j] ---------------------------
__global__ void bias_kernel(const float* __restrict__ b0, const float* __restrict__ b1,
                            const float* __restrict__ b2, const float* __restrict__ b3,
                            const float* __restrict__ r0, const float* __restrict__ r1,
                            const float* __restrict__ r2, const float* __restrict__ r3,
                            float* __restrict__ Bb) {
    int gid = blockIdx.x * 256 + threadIdx.x;        // 0..8191
    int g = gid >> 11, j = gid & 2047;
    const float *wb, *rb;
    switch (g) {
        case 0: wb = b0; rb = r0; break; case 1: wb = b1; rb = r1; break;
        case 2: wb = b2; rb = r2; break; default: wb = b3; rb = r3; break;
    }
    Bb[gid] = wb[j] + rb[j];
}

// ---- fused GEMM (4 gates) + sLSTM epilogue --------------------------------
// block: 512 threads = 8 waves; wave w: gate = w&3, rowgroup rg = w>>2.
// Wave computes a 128x64 tile of its gate (8x4 of 16x16x32 MFMA).
// grid: (16 row-tiles of 256, 32 col-tiles of 64); x fastest.
// LDS 160KB: A buffers @0,@32K,@64K (triple); B buffers @96K,@128K (double).
// XOR swizzle: chunk (r,jj) holds k-chunk jj^(r&7)  (conflict-free b128 reads).
// Pipeline (steady state, iter kt):
//   read A from a[kt%3], B from b[kt&1]
//   ph0: issue B(kt+1) x4 -> b[(kt+1)&1]
//   ph1: issue A(kt+2) x2 -> a[(kt+2)%3]     ph2: issue A(kt+2) x2
//   ph3: s_waitcnt vmcnt(4)  (retire A(kt+1)+B(kt+1); A(kt+2) stays in flight)
__global__ __launch_bounds__(512, 2) void slstm_kernel(
    const __hip_bfloat16* __restrict__ A,    // [4096][4096], W follows at +AW_OFS
    const float* __restrict__ Bb,            // [4][2048]
    const float* __restrict__ c_prev,
    const float* __restrict__ n_prev,
    const float* __restrict__ m_prev,
    float* __restrict__ out)                 // h | c | n | m
{
    __shared__ uint4 smem4[163840 / 16];     // 160 KB
    char* smem = (char*)smem4;

    const int tid  = threadIdx.x;
    const int lane = tid & 63;
    const int wv   = tid >> 6;     // wave id 0..7
    const int gate = wv & 3;
    const int rg   = wv >> 2;      // rowgroup 0/1 (128 rows each)
    const int lm   = lane & 15;
    const int quad = lane >> 4;
    const int l7   = lm & 7;

    const int row0 = blockIdx.x * 256;  // batch rows
    const int col0 = blockIdx.y * 64;   // hidden cols

    // fragment ds_read offsets (relative to buffer base); + mt/nt*2048 later
    int aoff[2], boff[2];
#pragma unroll
    for (int kk = 0; kk < 2; ++kk) {
        int cof = ((kk * 4 + quad) ^ l7) * 16;
        aoff[kk] = (rg * 128 + lm) * 128 + cof;
        boff[kk] = (gate * 64 + lm) * 128 + cof;
    }

    // staging: per wave 4 A-loads + 4 B-loads of 1KB (64 lanes x 16B) per tile.
    int agofs[4], bgofs[4], lbo[4];
#pragma unroll
    for (int t = 0; t < 4; ++t) {
        int idx = (wv * 4 + t) * 64 + lane;          // 0..2047
        int r = idx >> 3, jj = idx & 7;
        agofs[t] = (row0 + r) * KDIM + (jj ^ (r & 7)) * 8;
        int g = r >> 6, rr = r & 63;
        bgofs[t] = AW_OFS + (g * NHID + col0 + rr) * KDIM + (jj ^ (rr & 7)) * 8;
        lbo[t] = idx * 16;                           // LDS byte off within buffer
    }

    f32x4 acc[8][4];
#pragma unroll
    for (int mt = 0; mt < 8; ++mt)
#pragma unroll
        for (int nt = 0; nt < 4; ++nt)
#pragma unroll
            for (int r = 0; r < 4; ++r) acc[mt][nt][r] = 0.0f;

    // A triple buffer rotation: aR = A(kt), aN = A(kt+1), aN2 = write tgt A(kt+2)
    int aR = 0, aN = 32768, aN2 = 65536;
    // B double buffer: bR = B(kt), bW = write tgt B(kt+1)
    int bR = 98304, bW = 131072;

    // prologue: A(0)->aR, B(0)->bR, A(1)->aN; retire first 8, keep A(1) in flight
#pragma unroll
    for (int t = 0; t < 4; ++t) GL_LDS16(A + agofs[t], smem + aR + lbo[t]);
#pragma unroll
    for (int t = 0; t < 4; ++t) GL_LDS16(A + bgofs[t], smem + bR + lbo[t]);
#pragma unroll
    for (int t = 0; t < 4; ++t) GL_LDS16(A + agofs[t] + 64, smem + aN + lbo[t]);
    asm volatile("s_waitcnt vmcnt(4)" ::: "memory");
    __builtin_amdgcn_s_barrier();

    short8 bf[4];
    for (int kt = 0; kt < 64; ++kt) {
        const char* aB = smem + aR;
        const char* bB = smem + bR;
        char* aW = smem + aN2;
        char* bWp = smem + bW;
        const int kA = (kt + 2) * 64;
        const int kB = (kt + 1) * 64;
        const bool stA = kt <= 61, stB = kt <= 62;

#pragma unroll
        for (int p = 0; p < 4; ++p) {
            const int kk = p >> 1;      // phases 0,1: k 0-31; phases 2,3: k 32-63
            const int mh = p & 1;       // mt half 0-3 / 4-7
            if (p == 0 || p == 2) {
#pragma unroll
                for (int nt = 0; nt < 4; ++nt)
                    bf[nt] = *(const short8*)(bB + boff[kk] + nt * 2048);
            }
            short8 af[4];
#pragma unroll
            for (int m2 = 0; m2 < 4; ++m2)
                af[m2] = *(const short8*)(aB + aoff[kk] + (mh * 4 + m2) * 2048);

            if (p == 0 && stB) {
#pragma unroll
                for (int t = 0; t < 4; ++t) GL_LDS16(A + bgofs[t] + kB, bWp + lbo[t]);
            }
            if (p == 1 && stA) {
                GL_LDS16(A + agofs[0] + kA, aW + lbo[0]);
                GL_LDS16(A + agofs[1] + kA, aW + lbo[1]);
            }
            if (p == 2 && stA) {
                GL_LDS16(A + agofs[2] + kA, aW + lbo[2]);
                GL_LDS16(A + agofs[3] + kA, aW + lbo[3]);
            }
            if (p == 3 && kt < 63) {
                // retire A(kt+1) and B(kt+1); leave A(kt+2) (4 loads) in flight
                if (kt <= 61) asm volatile("s_waitcnt vmcnt(4)" ::: "memory");
                else          asm volatile("s_waitcnt vmcnt(0)" ::: "memory");
            }
            __builtin_amdgcn_s_barrier();
            __builtin_amdgcn_s_setprio(1);
#pragma unroll
            for (int m2 = 0; m2 < 4; ++m2)
#pragma unroll
                for (int nt = 0; nt < 4; ++nt)
                    acc[mh * 4 + m2][nt] = __builtin_amdgcn_mfma_f32_16x16x32_bf16(
                        af[m2], bf[nt], acc[mh * 4 + m2][nt], 0, 0, 0);
            __builtin_amdgcn_s_setprio(0);
            __builtin_amdgcn_s_barrier();
        }
        // rotate buffers: A triple, B double
        int t0 = aR; aR = aN; aN = aN2; aN2 = t0;
        int t1 = bR; bR = bW; bW = t1;
    }

    // ---- epilogue: exchange gate tiles through LDS, compute h,c,n,m ----
    float* exch = (float*)smem;   // [2 rg][4 gates][16 rows][65] floats (33.3KB)
#pragma unroll
    for (int mt = 0; mt < 8; ++mt) {
        __syncthreads();
#pragma unroll
        for (int nt = 0; nt < 4; ++nt)
#pragma unroll
            for (int r = 0; r < 4; ++r)
                exch[((rg * 4 + gate) * 16 + quad * 4 + r) * 65 + nt * 16 + lm] =
                    acc[mt][nt][r];
        __syncthreads();
#pragma unroll
        for (int q = 0; q < 4; ++q) {
            int e   = q * 512 + tid;          // 0..2047
            int erh = e >> 10, row = (e >> 6) & 15, col = e & 63;
            int R = row0 + erh * 128 + mt * 16 + row;
            int C = col0 + col;
            long idx = (long)R * NHID + C;
            float zp = exch[((erh * 4 + 0) * 16 + row) * 65 + col] + Bb[C];
            float ip = exch[((erh * 4 + 1) * 16 + row) * 65 + col] + Bb[2048 + C];
            float fp = exch[((erh * 4 + 2) * 16 + row) * 65 + col] + Bb[4096 + C];
            float op = exch[((erh * 4 + 3) * 16 + row) * 65 + col] + Bb[6144 + C];
            float cp = __builtin_nontemporal_load(c_prev + idx);
            float np = __builtin_nontemporal_load(n_prev + idx);
            float mp = __builtin_nontemporal_load(m_prev + idx);
            float z  = tanhf(zp);
            float o  = 1.0f / (1.0f + __expf(-op));
            float mm = fmaxf(fp + mp, ip);
            float ih = __expf(ip - mm);
            float fh = __expf(fp + mp - mm);
            float cc = fh * cp + ih * z;
            float nn = fh * np + ih;
            float hh = o * cc / nn;
            __builtin_nontemporal_store(hh, out + idx);
            __builtin_nontemporal_store(cc, out + NTOT + idx);
            __builtin_nontemporal_store(nn, out + 2 * NTOT + idx);
            __builtin_nontemporal_store(mm, out + 3 * NTOT + idx);
        }
    }
}

extern "C" void kernel_launch(void* const* d_in, const int* in_sizes, int n_in,
                              void* d_out, int out_size, void* d_ws, size_t ws_size,
                              hipStream_t stream) {
    const float* x      = (const float*)d_in[0];
    const float* h_prev = (const float*)d_in[1];
    const float* c_prev = (const float*)d_in[2];
    const float* n_prev = (const float*)d_in[3];
    const float* m_prev = (const float*)d_in[4];
    unsigned short* A  = (unsigned short*)d_ws;                          // 32 MB
    unsigned short* Wb = (unsigned short*)((char*)d_ws + 33554432);      // 64 MB
    float*          Bb = (float*)((char*)d_ws + 100663296);              // 32 KB

    convA_kernel<<<8192, 256, 0, stream>>>(x, h_prev, A);
    convW_kernel<<<dim3(2048, 8), 256, 0, stream>>>(
        (const float*)d_in[5], (const float*)d_in[7], (const float*)d_in[9],
        (const float*)d_in[11], (const float*)d_in[13], (const float*)d_in[15],
        (const float*)d_in[17], (const float*)d_in[19], Wb);
    bias_kernel<<<32, 256, 0, stream>>>(
        (const float*)d_in[6], (const float*)d_in[8], (const float*)d_in[10],
        (const float*)d_in[12], (const float*)d_in[14], (const float*)d_in[16],
        (const float*)d_in[18], (const float*)d_in[20], Bb);

    slstm_kernel<<<dim3(16, 32), 512, 0, stream>>>(
        (const __hip_bfloat16*)A, Bb, c_prev, n_prev, m_prev, (float*)d_out);
}